// Round 14
// baseline (417.881 us; speedup 1.0000x reference)
//
#include <hip/hip_runtime.h>
#include <hip/hip_bf16.h>

typedef float  f32x4 __attribute__((ext_vector_type(4)));
typedef short  s16x8 __attribute__((ext_vector_type(8)));

#define NB   1024
#define SEQ  64
#define DIM  512
#define NH   8
#define SCALE 0.044194173824159216f

// round-half-up f32->bf16: 2 VALU ops
static __device__ __forceinline__ unsigned short f2bf(float f) {
    unsigned u = __builtin_bit_cast(unsigned, f);
    return (unsigned short)((u + 0x8000u) >> 16);
}

static __device__ __forceinline__ f32x4 mma(s16x8 a, s16x8 b, f32x4 c) {
    return __builtin_amdgcn_mfma_f32_16x16x32_bf16(a, b, c, 0, 0, 0);
}

static __device__ __forceinline__ s16x8 cvt2(float4 a, float4 b) {
    s16x8 x;
    x[0] = (short)f2bf(a.x); x[1] = (short)f2bf(a.y);
    x[2] = (short)f2bf(a.z); x[3] = (short)f2bf(a.w);
    x[4] = (short)f2bf(b.x); x[5] = (short)f2bf(b.y);
    x[6] = (short)f2bf(b.z); x[7] = (short)f2bf(b.w);
    return x;
}

// Pre-kernel: Wq, Wc (f32 [512][512] row-major [k][n]) -> bf16 B-fragment order.
__global__ __launch_bounds__(256) void prep_weights(
    const float* __restrict__ Wq, const float* __restrict__ Wc,
    unsigned short* __restrict__ wf)
{
    int gid  = blockIdx.x * 256 + threadIdx.x;   // 0..65535
    int m    = gid >> 15;
    int tile = (gid >> 10) & 31;
    int ks   = (gid >> 6) & 15;
    int lane = gid & 63;
    const float* W = m ? Wc : Wq;
    int col = tile * 16 + (lane & 15);
    int k0  = ks * 32 + (lane >> 4) * 8;
    unsigned short* dst = wf + (size_t)gid * 8;
#pragma unroll
    for (int j = 0; j < 8; ++j)
        dst[j] = f2bf(W[(size_t)(k0 + j) * DIM + col]);
}

// ====================== Fused kernel: one block = (b, half) ======================
// 256 threads, 4 waves = heads half*4 .. half*4+3. LDS = 52 KB:
//   - 16 KB stage buffer, reused serially for 8 column-chunks {C0..C3,Q0..Q3}
//     (128 cols = 4 K-steps each), 1-deep prefetch: issue chunk n+1's loads ->
//     GEMM chunk n -> bar -> cvt+write -> bar. Cross-block overlap (2-3
//     blocks/CU co-resident) keeps HBM busy during MFMA phases — R13's
//     139 KB / 1-block-per-CU structure serialized read-stall and compute.
//   - 36 KB tail region: 4 per-wave 64x72 tiles (transpose staging, padded
//     stride -> ~2-way conflicts only).
// Stage swizzle (R12-verified involution, generalized): element (row,col) of
// a 128-col chunk lives at slot (p*512 + kk*256 + q*64 + row) ^ key, with
// p=col>>6, kk=(col>>5)&1, q=(col>>3)&3, key=(col>>3)&7. Writes are 2-way
// bank-aliased (free, m136); reads 8-distinct per phase (zero conflict).
// Sibling (b,half) blocks are orig-adjacent -> same XCD -> act reads L2-dedup.
// NOTE: plain __launch_bounds__ — a min-waves 2nd arg clamps the unified
// VGPR/AGPR budget below the 64-AGPR accumulator -> scratch spills
// (proved rounds 2 and 7: WRITE_SIZE +100 MB both times).
__global__ __launch_bounds__(256) void fused_half(
    const float* __restrict__ query,
    const float* __restrict__ context,
    const float* __restrict__ bq,
    const float* __restrict__ bc,
    const unsigned short* __restrict__ wf,
    float* __restrict__ out)
{
    __shared__ unsigned short smem[8192 + 18432];   // 16 KB stage + 36 KB tail
    unsigned short* stage = smem;

    const int tid  = threadIdx.x;
    const int lane = tid & 63;
    const int wv   = tid >> 6;          // 0..3
    const int l15  = lane & 15;
    const int l4   = lane >> 4;

    // XCD swizzle (grid 2048, %8==0 bijective); the two halves of one b are
    // orig-adjacent -> same XCD L2.
    const int i    = blockIdx.x;
    const int orig = (i & 7) * 256 + (i >> 3);
    const int b    = orig >> 1;
    const int half = orig & 1;
    const int h    = half * 4 + wv;

    const float* gq = query   + (size_t)b * SEQ * DIM;
    const float* gc = context + (size_t)b * SEQ * DIM;

    // staging map: thread covers row = tid>>2, cols {g*32 + cw*8 .. +7}, g=0..3
    const int row = tid >> 2;
    const int cw  = tid & 3;

    unsigned short (*T)[72] = (unsigned short(*)[72])(smem + 8192 + wv * 4608);

    float4 ld[8];

#define LOAD8(SRC, BASE)                                                       \
    {                                                                          \
        const float* p0_ = (SRC) + (size_t)row * DIM + (BASE) + cw * 8;        \
        _Pragma("unroll")                                                      \
        for (int g = 0; g < 4; ++g) {                                          \
            ld[2 * g]     = *(const float4*)(p0_ + g * 32);                    \
            ld[2 * g + 1] = *(const float4*)(p0_ + g * 32 + 4);                \
        }                                                                      \
    }

#define WRITE8()                                                               \
    {                                                                          \
        _Pragma("unroll")                                                      \
        for (int g = 0; g < 4; ++g) {                                          \
            const int s_ = (g >> 1) * 512 + (g & 1) * 256 + cw * 64 + row;     \
            const int k_ = 4 * (g & 1) + cw;                                   \
            *(s16x8*)&stage[(s_ ^ k_) * 8] = cvt2(ld[2 * g], ld[2 * g + 1]);   \
        }                                                                      \
    }

#define GEMM4(WFM, KBASE)                                                      \
    {                                                                          \
        _Pragma("unroll")                                                      \
        for (int ksl = 0; ksl < 4; ++ksl) {                                    \
            const int p_ = ksl >> 1, kk_ = ksl & 1;                            \
            s16x8 af[4], bf[4];                                                \
            _Pragma("unroll")                                                  \
            for (int mt = 0; mt < 4; ++mt) {                                   \
                const int s_ = p_ * 512 + kk_ * 256 + l4 * 64 + mt * 16 + l15; \
                af[mt] = *(const s16x8*)&stage[(s_ ^ (4 * kk_ + l4)) * 8];     \
            }                                                                  \
            _Pragma("unroll")                                                  \
            for (int nt = 0; nt < 4; ++nt)                                     \
                bf[nt] = *(const s16x8*)((WFM) +                               \
                    ((size_t)((h * 4 + nt) * 16 + (KBASE) + ksl) * 64 + lane) * 8); \
            _Pragma("unroll")                                                  \
            for (int mt = 0; mt < 4; ++mt)                                     \
                _Pragma("unroll")                                              \
                for (int nt = 0; nt < 4; ++nt)                                 \
                    acc[mt][nt] = mma(af[mt], bf[nt], acc[mt][nt]);            \
        }                                                                      \
    }

    const f32x4 fz = {0.f, 0.f, 0.f, 0.f};
    f32x4 acc[4][4];
#pragma unroll
    for (int x = 0; x < 4; ++x)
#pragma unroll
        for (int y = 0; y < 4; ++y) acc[x][y] = fz;

    // ---------------- C projection over 4 chunks ----------------
    LOAD8(gc, 0);
    WRITE8();
    __syncthreads();
#pragma unroll
    for (int c = 0; c < 4; ++c) {
        if (c < 3) { LOAD8(gc, (c + 1) * 128); }
        else       { LOAD8(gq, 0); }
        GEMM4(wf + 262144, c * 4);
        __syncthreads();
        WRITE8();                     // stages chunk c+1 (or Q0 at c==3)
        __syncthreads();
    }

    // Cp + bias -> per-wave tail tile; cb frags (Cp^T B-operand = contig rows)
#pragma unroll
    for (int nt = 0; nt < 4; ++nt) {
        float bcv = bc[h * 64 + nt * 16 + l15];
#pragma unroll
        for (int mt = 0; mt < 4; ++mt)
#pragma unroll
            for (int r = 0; r < 4; ++r)
                T[mt * 16 + l4 * 4 + r][nt * 16 + l15] = f2bf(acc[mt][nt][r] + bcv);
    }
    s16x8 cb[4][2];
#pragma unroll
    for (int nt = 0; nt < 4; ++nt)
#pragma unroll
        for (int ks = 0; ks < 2; ++ks)
            cb[nt][ks] = *(const s16x8*)&T[nt * 16 + l15][ks * 32 + l4 * 8];

    // ---------------- Q projection over 4 chunks (same acc regs) ----------------
#pragma unroll
    for (int x = 0; x < 4; ++x)
#pragma unroll
        for (int y = 0; y < 4; ++y) acc[x][y] = fz;
#pragma unroll
    for (int c = 0; c < 4; ++c) {
        if (c < 3) { LOAD8(gq, (c + 1) * 128); }
        GEMM4(wf, c * 4);
        if (c < 3) {
            __syncthreads();
            WRITE8();
            __syncthreads();
        }
    }

    // Qp + bias -> T (overwrites Cp; cb already in regs); qa/qb frags
#pragma unroll
    for (int nt = 0; nt < 4; ++nt) {
        float bqv = bq[h * 64 + nt * 16 + l15];
#pragma unroll
        for (int mt = 0; mt < 4; ++mt)
#pragma unroll
            for (int r = 0; r < 4; ++r)
                T[mt * 16 + l4 * 4 + r][nt * 16 + l15] = f2bf(acc[mt][nt][r] + bqv);
    }
    s16x8 qa[4][2], qb[4][2];
#pragma unroll
    for (int mt = 0; mt < 4; ++mt)
#pragma unroll
        for (int ks = 0; ks < 2; ++ks)
            qa[mt][ks] = *(const s16x8*)&T[mt * 16 + l15][ks * 32 + l4 * 8];
#pragma unroll
    for (int nt = 0; nt < 4; ++nt)
#pragma unroll
        for (int ks = 0; ks < 2; ++ks) {
            s16x8 v;
#pragma unroll
            for (int j = 0; j < 8; ++j)
                v[j] = (short)T[ks * 32 + l4 * 8 + j][nt * 16 + l15];
            qb[nt][ks] = v;
        }

    // ---------------- attention tail (R3/R13-proven) ----------------
    f32x4 Sc[4][4];
#pragma unroll
    for (int x = 0; x < 4; ++x)
#pragma unroll
        for (int y = 0; y < 4; ++y) Sc[x][y] = fz;
#pragma unroll
    for (int ks = 0; ks < 2; ++ks)
#pragma unroll
        for (int mt = 0; mt < 4; ++mt)
#pragma unroll
            for (int nt = 0; nt < 4; ++nt)
                Sc[mt][nt] = mma(qa[mt][ks], cb[nt][ks], Sc[mt][nt]);

    // softmax over keys (rows): P1 -> T
#pragma unroll
    for (int mt = 0; mt < 4; ++mt)
#pragma unroll
        for (int r = 0; r < 4; ++r) {
            float m = fmaxf(fmaxf(Sc[mt][0][r], Sc[mt][1][r]),
                            fmaxf(Sc[mt][2][r], Sc[mt][3][r]));
            m = fmaxf(m, __shfl_xor(m, 1));
            m = fmaxf(m, __shfl_xor(m, 2));
            m = fmaxf(m, __shfl_xor(m, 4));
            m = fmaxf(m, __shfl_xor(m, 8));
            float e[4], s = 0.f;
#pragma unroll
            for (int nt = 0; nt < 4; ++nt) { e[nt] = __expf(SCALE * (Sc[mt][nt][r] - m)); s += e[nt]; }
            s += __shfl_xor(s, 1);
            s += __shfl_xor(s, 2);
            s += __shfl_xor(s, 4);
            s += __shfl_xor(s, 8);
            float inv = 1.f / s;
            int r3 = mt * 16 + l4 * 4 + r;
#pragma unroll
            for (int nt = 0; nt < 4; ++nt)
                T[r3][nt * 16 + l15] = f2bf(e[nt] * inv);
        }

    s16x8 pa[4][2];
#pragma unroll
    for (int mt = 0; mt < 4; ++mt)
#pragma unroll
        for (int ks = 0; ks < 2; ++ks)
            pa[mt][ks] = *(const s16x8*)&T[mt * 16 + l15][ks * 32 + l4 * 8];

    // softmax over queries (cols): P2^T -> T
#pragma unroll
    for (int nt = 0; nt < 4; ++nt) {
        float m = -1e30f;
#pragma unroll
        for (int mt = 0; mt < 4; ++mt)
#pragma unroll
            for (int r = 0; r < 4; ++r) m = fmaxf(m, Sc[mt][nt][r]);
        m = fmaxf(m, __shfl_xor(m, 16));
        m = fmaxf(m, __shfl_xor(m, 32));
        float ee[4][4], s = 0.f;
#pragma unroll
        for (int mt = 0; mt < 4; ++mt)
#pragma unroll
            for (int r = 0; r < 4; ++r) { ee[mt][r] = __expf(SCALE * (Sc[mt][nt][r] - m)); s += ee[mt][r]; }
        s += __shfl_xor(s, 16);
        s += __shfl_xor(s, 32);
        float inv = 1.f / s;
        int krow = nt * 16 + l15;
#pragma unroll
        for (int mt = 0; mt < 4; ++mt)
#pragma unroll
            for (int r = 0; r < 4; ++r)
                T[krow][mt * 16 + l4 * 4 + r] = f2bf(ee[mt][r] * inv);
    }

    // c_coattn = P1 @ Cp^T ; store
    f32x4 O[4][4];
#pragma unroll
    for (int x = 0; x < 4; ++x)
#pragma unroll
        for (int y = 0; y < 4; ++y) O[x][y] = fz;
#pragma unroll
    for (int ks = 0; ks < 2; ++ks)
#pragma unroll
        for (int mt = 0; mt < 4; ++mt)
#pragma unroll
            for (int nt = 0; nt < 4; ++nt)
                O[mt][nt] = mma(pa[mt][ks], cb[nt][ks], O[mt][nt]);

    float* cO = out;
#pragma unroll
    for (int mt = 0; mt < 4; ++mt)
#pragma unroll
        for (int nt = 0; nt < 4; ++nt)
#pragma unroll
            for (int r = 0; r < 4; ++r) {
                int qrow = mt * 16 + l4 * 4 + r;
                cO[((size_t)b * SEQ + qrow) * (NH * 64) + h * 64 + nt * 16 + l15] = O[mt][nt][r];
            }

    // q_coattn = P2^T @ Qp ; store
    s16x8 p2a[4][2];
#pragma unroll
    for (int mt = 0; mt < 4; ++mt)
#pragma unroll
        for (int ks = 0; ks < 2; ++ks)
            p2a[mt][ks] = *(const s16x8*)&T[mt * 16 + l15][ks * 32 + l4 * 8];

#pragma unroll
    for (int x = 0; x < 4; ++x)
#pragma unroll
        for (int y = 0; y < 4; ++y) O[x][y] = fz;
#pragma unroll
    for (int ks = 0; ks < 2; ++ks)
#pragma unroll
        for (int mt = 0; mt < 4; ++mt)
#pragma unroll
            for (int nt = 0; nt < 4; ++nt)
                O[mt][nt] = mma(p2a[mt][ks], qb[nt][ks], O[mt][nt]);

    float* qO = out + (size_t)NB * SEQ * NH * 64;
#pragma unroll
    for (int mt = 0; mt < 4; ++mt)
#pragma unroll
        for (int nt = 0; nt < 4; ++nt)
#pragma unroll
            for (int r = 0; r < 4; ++r) {
                int krow = mt * 16 + l4 * 4 + r;
                qO[((size_t)b * SEQ + krow) * (NH * 64) + h * 64 + nt * 16 + l15] = O[mt][nt][r];
            }

#undef LOAD8
#undef WRITE8
#undef GEMM4
}

extern "C" void kernel_launch(void* const* d_in, const int* in_sizes, int n_in,
                              void* d_out, int out_size, void* d_ws, size_t ws_size,
                              hipStream_t stream) {
    const float* query   = (const float*)d_in[0];
    const float* context = (const float*)d_in[1];
    const float* Wq      = (const float*)d_in[2];
    const float* bq      = (const float*)d_in[3];
    const float* Wc      = (const float*)d_in[4];
    const float* bc      = (const float*)d_in[5];
    float* out = (float*)d_out;

    unsigned short* wfrag = (unsigned short*)d_ws;   // 1 MB bf16 weight frags

    prep_weights<<<256, 256, 0, stream>>>(Wq, Wc, wfrag);
    fused_half<<<NB * 2, 256, 0, stream>>>(query, context, bq, bc, wfrag, out);
}